// Round 1
// baseline (594.620 us; speedup 1.0000x reference)
//
#include <hip/hip_runtime.h>
#include <hip/hip_bf16.h>

#define IND   1024
#define OUTD  128
#define BATCH 65536
#define BM    128
#define BK    64

typedef __bf16 bf16x8 __attribute__((ext_vector_type(8)));
typedef float  f32x4  __attribute__((ext_vector_type(4)));

__device__ __forceinline__ unsigned short f2bf(float f) {
    unsigned u = __float_as_uint(f);
    u += 0x7FFF + ((u >> 16) & 1);          // round-to-nearest-even
    return (unsigned short)(u >> 16);
}
__device__ __forceinline__ unsigned pack2(float a, float b) {
    return (unsigned)f2bf(a) | ((unsigned)f2bf(b) << 16);
}

// ---------------- weight row normalization: one block per (half,row) ----------------
// OWNNorm with per-row groups == mean-center each row then L2-normalize.
__global__ __launch_bounds__(256) void norm_rows_kernel(
    const float* __restrict__ fcw, unsigned short* __restrict__ wn)
{
    __shared__ float red[8];
    const int b    = blockIdx.x;          // 0..255
    const int half = b >> 7, row = b & 127;
    const int t    = threadIdx.x;
    const float* src = fcw + (size_t)row * (2 * IND) + half * IND;

    float v[4];
#pragma unroll
    for (int j = 0; j < 4; ++j) v[j] = src[t + j * 256];

    // block reduce: sum
    float s = v[0] + v[1] + v[2] + v[3];
#pragma unroll
    for (int o = 32; o; o >>= 1) s += __shfl_down(s, o);
    if ((t & 63) == 0) red[t >> 6] = s;
    __syncthreads();
    const float mean = (red[0] + red[1] + red[2] + red[3]) * (1.0f / IND);

    float c[4];
    float ss = 0.0f;
#pragma unroll
    for (int j = 0; j < 4; ++j) { c[j] = v[j] - mean; ss += c[j] * c[j]; }
    __syncthreads();   // red[0..3] fully consumed above
#pragma unroll
    for (int o = 32; o; o >>= 1) ss += __shfl_down(ss, o);
    if ((t & 63) == 0) red[4 + (t >> 6)] = ss;
    __syncthreads();
    const float scale = rsqrtf(red[4] + red[5] + red[6] + red[7]);

    unsigned short* dst = wn + (size_t)(half * 128 + row) * IND;
#pragma unroll
    for (int j = 0; j < 4; ++j) dst[t + j * 256] = f2bf(c[j] * scale);
}

// ---------------- fused dual GEMM + affine combine ----------------
// Block: 256 threads (4 waves, 2x2). Tile M=128 x N=128 (full outdim), BK=64.
// x-phases use LDS buf0, y-phases buf1 -> implicit double buffering, 1 barrier/phase.

#define LOAD_TILES(AP, WP)                                                    \
    {                                                                         \
        _Pragma("unroll")                                                     \
        for (int it = 0; it < 8; ++it)                                        \
            av[it] = *(const float4*)((AP) + (size_t)(rA + it * 16) * IND + cA); \
        _Pragma("unroll")                                                     \
        for (int it = 0; it < 4; ++it)                                        \
            wv[it] = *(const uint4*)((WP) + (size_t)(rW + it * 32) * IND + cW);  \
    }

#define WRITE_TILES(BUF)                                                      \
    {                                                                         \
        _Pragma("unroll")                                                     \
        for (int it = 0; it < 8; ++it) {                                      \
            const int row = rA + it * 16;                                     \
            const int idx = (row * BK + cA) ^ ((row & 7) << 3);               \
            uint2 u;                                                          \
            u.x = pack2(av[it].x, av[it].y);                                  \
            u.y = pack2(av[it].z, av[it].w);                                  \
            *(uint2*)(&lds[BUF][0][idx]) = u;                                 \
        }                                                                     \
        _Pragma("unroll")                                                     \
        for (int it = 0; it < 4; ++it) {                                      \
            const int row = rW + it * 32;                                     \
            const int idx = (row * BK + cW) ^ ((row & 7) << 3);               \
            *(uint4*)(&lds[BUF][1][idx]) = wv[it];                            \
        }                                                                     \
    }

#define COMPUTE_PHASE(BUF, ACC)                                               \
    {                                                                         \
        _Pragma("unroll")                                                     \
        for (int kk = 0; kk < 2; ++kk) {                                      \
            bf16x8 af[4], bfr[4];                                             \
            _Pragma("unroll")                                                 \
            for (int i = 0; i < 4; ++i) {                                     \
                const int row = wm * 64 + i * 16 + lr;                        \
                const int idx = (row * BK + kk * 32 + lk) ^ swz;              \
                af[i] = *(const bf16x8*)(&lds[BUF][0][idx]);                  \
            }                                                                 \
            _Pragma("unroll")                                                 \
            for (int n = 0; n < 4; ++n) {                                     \
                const int row = wn * 64 + n * 16 + lr;                        \
                const int idx = (row * BK + kk * 32 + lk) ^ swz;              \
                bfr[n] = *(const bf16x8*)(&lds[BUF][1][idx]);                 \
            }                                                                 \
            _Pragma("unroll")                                                 \
            for (int i = 0; i < 4; ++i)                                       \
                _Pragma("unroll")                                             \
                for (int n = 0; n < 4; ++n)                                   \
                    ACC[i][n] = __builtin_amdgcn_mfma_f32_16x16x32_bf16(      \
                        af[i], bfr[n], ACC[i][n], 0, 0, 0);                   \
        }                                                                     \
    }

__global__ __launch_bounds__(256, 2) void fused_gemm_kernel(
    const float* __restrict__ x, const float* __restrict__ y,
    const unsigned short* __restrict__ w0, const unsigned short* __restrict__ w1,
    const float* __restrict__ bias, const float* __restrict__ a0,
    const float* __restrict__ a1, float* __restrict__ out)
{
    __shared__ __align__(16) unsigned short lds[2][2][BM * BK]; // [buf][0=A,1=W] 64 KiB

    const int t    = threadIdx.x;
    const int lane = t & 63;
    const int wave = t >> 6;
    const int wm   = wave >> 1, wn = wave & 1;
    const size_t m0 = (size_t)blockIdx.x * BM;

    // staging coords
    const int rA = t >> 4;          // + it*16  (A rows)
    const int cA = (t & 15) * 4;    // f32 col within BK
    const int rW = t >> 3;          // + it*32  (W rows)
    const int cW = (t & 7) * 8;     // ushort col within BK

    // fragment coords
    const int lr  = lane & 15;
    const int lk  = (lane >> 4) * 8;
    const int swz = (lr & 7) << 3;

    f32x4 acc0[4][4], acc1[4][4];
#pragma unroll
    for (int i = 0; i < 4; ++i)
#pragma unroll
        for (int n = 0; n < 4; ++n) { acc0[i][n] = 0; acc1[i][n] = 0; }

    float4 av[8];
    uint4  wv[4];

    // prologue: stage x ks=0 into buf0
    LOAD_TILES(x + m0 * IND, w0);
    WRITE_TILES(0);
    __syncthreads();

    for (int ks = 0; ks < 16; ++ks) {
        // phase A: compute x (buf0), stage y[ks] -> buf1
        LOAD_TILES(y + m0 * IND + ks * BK, w1 + ks * BK);
        COMPUTE_PHASE(0, acc0);
        WRITE_TILES(1);
        __syncthreads();

        // phase B: compute y (buf1), stage x[ks+1] -> buf0
        if (ks < 15) { LOAD_TILES(x + m0 * IND + (ks + 1) * BK, w0 + (ks + 1) * BK); }
        COMPUTE_PHASE(1, acc1);
        if (ks < 15) { WRITE_TILES(0); }
        __syncthreads();
    }

    // epilogue: write out0, out1, combined
    float s0[4], s1[4], bb[4];
    int   col[4];
#pragma unroll
    for (int n = 0; n < 4; ++n) {
        col[n] = wn * 64 + n * 16 + lr;
        s0[n]  = a0[col[n]];
        s1[n]  = a1[col[n]];
        bb[n]  = bias[col[n]];
    }
    float* out0 = out;
    float* out1 = out + (size_t)BATCH * OUTD;
    float* outc = out + 2 * (size_t)BATCH * OUTD;
    const int rbase = wm * 64 + (lane >> 4) * 4;
#pragma unroll
    for (int i = 0; i < 4; ++i) {
#pragma unroll
        for (int j = 0; j < 4; ++j) {
            const size_t off = (m0 + rbase + i * 16 + j) * OUTD;
#pragma unroll
            for (int n = 0; n < 4; ++n) {
                const float o0 = acc0[i][n][j];
                const float o1 = acc1[i][n][j];
                out0[off + col[n]] = o0;
                out1[off + col[n]] = o1;
                outc[off + col[n]] = o0 * s0[n] + o1 * s1[n] + bb[n];
            }
        }
    }
}

extern "C" void kernel_launch(void* const* d_in, const int* in_sizes, int n_in,
                              void* d_out, int out_size, void* d_ws, size_t ws_size,
                              hipStream_t stream)
{
    const float* x   = (const float*)d_in[0];
    const float* y   = (const float*)d_in[1];
    const float* fcw = (const float*)d_in[2];
    const float* fcb = (const float*)d_in[3];
    const float* a0  = (const float*)d_in[4];
    const float* a1  = (const float*)d_in[5];

    unsigned short* wn = (unsigned short*)d_ws;   // [2][128][1024] bf16 normalized weights

    hipLaunchKernelGGL(norm_rows_kernel, dim3(256), dim3(256), 0, stream, fcw, wn);
    hipLaunchKernelGGL(fused_gemm_kernel, dim3(BATCH / BM), dim3(256), 0, stream,
                       x, y, wn, wn + (size_t)128 * IND, fcb, a0, a1, (float*)d_out);
}